// Round 6
// baseline (233.961 us; speedup 1.0000x reference)
//
#include <hip/hip_runtime.h>
#include <hip/hip_bf16.h>

// MambaStateSpaceLayer: B=2, S=1024, D_MODEL=1024, D_STATE=16, D_INNER=2048
// Round 6: r3 GEMM geometry (BM=128/MI=4, 768 blocks) + 2-phase LDS double-buffer
// (STAGE next before compute cur, one barrier/iter); gemm3 K-split x4 + dbuf.

#define LOG2E 1.4426950408889634f

typedef float floatx4 __attribute__((ext_vector_type(4)));
typedef short short8 __attribute__((ext_vector_type(8)));

__device__ __forceinline__ float fexp2(float x) { return __builtin_amdgcn_exp2f(x); }
__device__ __forceinline__ unsigned short f2bf(float f) {
    unsigned int u = __float_as_uint(f);
    u = (u + 0x7fffu + ((u >> 16) & 1u)) >> 16;   // round-to-nearest-even
    return (unsigned short)u;
}
__device__ __forceinline__ float bf2f(unsigned short h) {
    return __uint_as_float(((unsigned int)h) << 16);
}

// async 16B global -> LDS. lp MUST be wave-uniform (HW adds lane*16).
#define GLDS16(gp, lp) __builtin_amdgcn_global_load_lds(                      \
    (const __attribute__((address_space(1))) void*)(gp),                      \
    (__attribute__((address_space(3))) void*)(lp), 16, 0, 0)

// ------- cast x, W_gate, W_in, W_out to bf16 + init out=bias (one kernel) ----
__global__ __launch_bounds__(256) void cast_and_init(
    const float* __restrict__ x, const float* __restrict__ wg,
    const float* __restrict__ wi, const float* __restrict__ wo,
    unsigned short* __restrict__ ox, unsigned short* __restrict__ owg,
    unsigned short* __restrict__ owi, unsigned short* __restrict__ owo,
    const float* __restrict__ b_out, float* __restrict__ out)
{
    const int bid = blockIdx.x;
    if (bid < 10240) {
        const size_t e = ((size_t)bid * 256 + threadIdx.x) * 4;
        const float* src; unsigned short* dst; size_t off;
        if (e < 2097152)      { src = x;  dst = ox;  off = e; }
        else if (e < 4194304) { src = wg; dst = owg; off = e - 2097152; }
        else if (e < 8388608) { src = wi; dst = owi; off = e - 4194304; }
        else                  { src = wo; dst = owo; off = e - 8388608; }
        float4 v = *(const float4*)(src + off);
        *(ushort4*)(dst + off) = make_ushort4(f2bf(v.x), f2bf(v.y), f2bf(v.z), f2bf(v.w));
    } else {
        const size_t e = ((size_t)(bid - 10240) * 256 + threadIdx.x) * 4;
        const int col = (int)(e & 1023);
        *(float4*)(out + e) = *(const float4*)(b_out + col);
    }
}

// ---------------- MFMA GEMM, 2-phase double-buffered -------------------------
// C = A[M,ldk] @ W[N,ldk]^T (+ bias).  BK=64 bf16 (128B rows, 8x16B slots).
// Staging: global_load_lds dwordx4, linear LDS dest; source slot pre-swizzled
// (l&7)^(l>>3); ds_read uses slot ^ (row&7)  [both-sides-or-neither].
// Schedule per iter: STAGE(next buf) ; ds_read+MFMA(cur buf) ; barrier.
// One barrier/iter is sufficient: lgkmcnt(0) before MFMA means all reads of
// cur are done by the barrier; staging of cur^1 happens before others read it
// only after the barrier.
// Block = 4 waves (2x2). Wave tile = (MI*16) x 64. BM = MI*32, BN = 128.
// MODE 3 (MI=4): fused input GEMM. blockIdx.x<16 -> gate=sigmoid->bf16;
//         else proj: n<2048 -> xproj f32 ; n>=2048 -> relu -> delta f32.
// MODE 2 (MI=2): K-split over blockIdx.z (Ksub each); atomicAdd f32 into outp.
template <int MODE, int MI>
__global__ __launch_bounds__(256, 2) void gemm_mfma(
    const unsigned short* __restrict__ A,
    const unsigned short* __restrict__ W0,
    const unsigned short* __restrict__ W1,
    const float* __restrict__ bias0, const float* __restrict__ bias1,
    unsigned short* __restrict__ gate,
    float* __restrict__ xproj, float* __restrict__ delta,
    float* __restrict__ outp, int ldk, int Ksub)
{
    constexpr int BM = MI * 32;
    constexpr int ROWA = BM / 32;          // A 1KB staging blocks per wave
    __shared__ short As[2][BM * 64];
    __shared__ short Bs[2][128 * 64];

    const int tid = threadIdx.x;
    const int l = tid & 63, w = tid >> 6;
    const int mbase = blockIdx.y * BM;
    const int kbeg = (MODE == 2) ? blockIdx.z * Ksub : 0;
    const int kend = kbeg + Ksub;

    const unsigned short* Wp; const float* bias = nullptr; int nbase; bool isGate = false;
    if (MODE == 3) {
        const int bx = blockIdx.x;
        if (bx < 16) { Wp = W0; bias = bias0; nbase = bx * 128; isGate = true; }
        else         { Wp = W1; bias = bias1; nbase = (bx - 16) * 128; }
    } else { Wp = W0; nbase = blockIdx.x * 128; }

    // per-lane staging source offsets (elements, k0 added per use)
    const int rl = l >> 3;                 // row within 8-row block
    const int cs = (l & 7) ^ rl;           // inverse-swizzled source slot
    size_t aoff[ROWA], boff[4];
    #pragma unroll
    for (int j = 0; j < ROWA; ++j)
        aoff[j] = (size_t)(mbase + (w * ROWA + j) * 8 + rl) * ldk + cs * 8;
    #pragma unroll
    for (int j = 0; j < 4; ++j)
        boff[j] = (size_t)(nbase + (w * 4 + j) * 8 + rl) * ldk + cs * 8;

    auto STAGE = [&](int buf, int k0) {
        #pragma unroll
        for (int j = 0; j < ROWA; ++j)
            GLDS16(A + aoff[j] + k0, &As[buf][(w * ROWA + j) * 512]);
        #pragma unroll
        for (int j = 0; j < 4; ++j)
            GLDS16(Wp + boff[j] + k0, &Bs[buf][(w * 4 + j) * 512]);
    };

    const int wm = (w >> 1) * (MI * 16), wn = (w & 1) * 64;
    floatx4 acc[MI][4] = {};

    STAGE(0, kbeg);
    __syncthreads();                       // vmcnt(0) drained by compiler

    int cur = 0;
    for (int k0 = kbeg; k0 < kend; k0 += 64) {
        if (k0 + 64 < kend) STAGE(cur ^ 1, k0 + 64);   // prefetch next tile

        #pragma unroll
        for (int kk = 0; kk < 2; ++kk) {
            short8 af[MI], bfr[4];
            #pragma unroll
            for (int i = 0; i < MI; ++i) {
                const int row = wm + i * 16 + (l & 15);
                af[i] = *(const short8*)&As[cur][row * 64 + (((kk * 4 + (l >> 4)) ^ (row & 7)) << 3)];
            }
            #pragma unroll
            for (int j = 0; j < 4; ++j) {
                const int row = wn + j * 16 + (l & 15);
                bfr[j] = *(const short8*)&Bs[cur][row * 64 + (((kk * 4 + (l >> 4)) ^ (row & 7)) << 3)];
            }
            #pragma unroll
            for (int i = 0; i < MI; ++i)
                #pragma unroll
                for (int j = 0; j < 4; ++j)
                    acc[i][j] = __builtin_amdgcn_mfma_f32_16x16x32_bf16(af[i], bfr[j], acc[i][j], 0, 0, 0);
        }
        __syncthreads();                   // next tile staged; cur reads done
        cur ^= 1;
    }

    // epilogue: D col = lane&15, row = (lane>>4)*4 + reg  [m89-verified]
    const int crow0 = wm + (l >> 4) * 4;
    const int ccol = wn + (l & 15);
    #pragma unroll
    for (int j = 0; j < 4; ++j) {
        const int n = nbase + ccol + j * 16;
        const float bb = (MODE == 2) ? 0.0f : bias[n];
        #pragma unroll
        for (int i = 0; i < MI; ++i) {
            const int mr = mbase + crow0 + i * 16;
            #pragma unroll
            for (int r = 0; r < 4; ++r) {
                const float v = acc[i][j][r] + bb;
                const int m = mr + r;
                if (MODE == 3) {
                    if (isGate) {
                        const float s = 1.0f / (1.0f + fexp2(-v * LOG2E));
                        gate[(size_t)m * 2048 + n] = f2bf(s);
                    } else if (n < 2048) {
                        xproj[(size_t)m * 2048 + n] = v;
                    } else {
                        delta[(size_t)m * 2048 + (n - 2048)] = fmaxf(v, 0.0f);
                    }
                } else {
                    atomicAdd(&outp[(size_t)m * 1024 + n], v);
                }
            }
        }
    }
}

// ---------------- chunked selective scan (f32 xp/dl) -------------------------
constexpr int NC = 32, CL = 32;

__global__ __launch_bounds__(256) void scan_phaseA(
    const float* __restrict__ xp, const float* __restrict__ dl,
    const float* __restrict__ A_log, const float* __restrict__ B_mat,
    float* __restrict__ Q, float* __restrict__ sumdt)
{
    const int ch = blockIdx.x * 256 + threadIdx.x;
    const int c = blockIdx.y;
    const int d = ch & 2047, b = ch >> 11;
    float Ac[16], Bv[16], h[16];
    #pragma unroll
    for (int s = 0; s < 16; ++s) {
        Ac[s] = -fexp2(A_log[d * 16 + s] * LOG2E) * LOG2E;
        Bv[s] = B_mat[d * 16 + s];
        h[s] = 0.0f;
    }
    float sd = 0.0f;
    size_t idx = ((size_t)b * 1024 + (size_t)c * CL) * 2048 + d;
    for (int t = 0; t < CL; ++t, idx += 2048) {
        const float xt = xp[idx], dt = dl[idx];
        sd += dt;
        const float xdt = xt * dt;
        #pragma unroll
        for (int s = 0; s < 16; ++s)
            h[s] = fmaf(h[s], fexp2(Ac[s] * dt), xdt * Bv[s]);
    }
    float* q = Q + ((size_t)ch * NC + c) * 16;
    #pragma unroll
    for (int s = 0; s < 16; ++s) q[s] = h[s];
    sumdt[ch * NC + c] = sd;
}

__global__ __launch_bounds__(256) void scan_phaseB(
    const float* __restrict__ A_log, const float* __restrict__ Q,
    const float* __restrict__ sumdt, float* __restrict__ hst)
{
    const int s = threadIdx.x & 15;
    const int ch = blockIdx.x * 16 + (threadIdx.x >> 4);
    const int d = ch & 2047;
    const float Ac = -fexp2(A_log[d * 16 + s] * LOG2E) * LOG2E;
    float h = 0.0f;
    const float* q = Q + (size_t)ch * NC * 16 + s;
    const float* sd = sumdt + ch * NC;
    float* hs = hst + (size_t)ch * NC * 16 + s;
    for (int c = 0; c < NC; ++c) {
        hs[c * 16] = h;
        h = fmaf(h, fexp2(Ac * sd[c]), q[c * 16]);
    }
}

__global__ __launch_bounds__(256) void scan_phaseC(
    const float* __restrict__ xp, const float* __restrict__ dl,
    const float* __restrict__ A_log, const float* __restrict__ B_mat,
    const float* __restrict__ C_mat, const float* __restrict__ D_vec,
    const unsigned short* __restrict__ gate, const float* __restrict__ hst,
    unsigned short* __restrict__ z)
{
    const int ch = blockIdx.x * 256 + threadIdx.x;
    const int c = blockIdx.y;
    const int d = ch & 2047, b = ch >> 11;
    float Ac[16], Bv[16], Cv[16], h[16];
    #pragma unroll
    for (int s = 0; s < 16; ++s) {
        Ac[s] = -fexp2(A_log[d * 16 + s] * LOG2E) * LOG2E;
        Bv[s] = B_mat[d * 16 + s];
        Cv[s] = C_mat[s];
        h[s] = hst[((size_t)ch * NC + c) * 16 + s];
    }
    const float Dv = D_vec[d];
    size_t idx = ((size_t)b * 1024 + (size_t)c * CL) * 2048 + d;
    for (int t = 0; t < CL; ++t, idx += 2048) {
        const float xt = xp[idx], dt = dl[idx];
        const float xdt = xt * dt;
        float y = 0.0f;
        #pragma unroll
        for (int s = 0; s < 16; ++s) {
            h[s] = fmaf(h[s], fexp2(Ac[s] * dt), xdt * Bv[s]);
            y = fmaf(h[s], Cv[s], y);
        }
        const float g = bf2f(gate[idx]);
        z[idx] = f2bf(g * (y + xt * Dv));
    }
}

// ---------------------------------------------------------------------------
extern "C" void kernel_launch(void* const* d_in, const int* in_sizes, int n_in,
                              void* d_out, int out_size, void* d_ws, size_t ws_size,
                              hipStream_t stream) {
    const float* x      = (const float*)d_in[0];
    const float* W_in   = (const float*)d_in[1];
    const float* b_in   = (const float*)d_in[2];
    const float* W_gate = (const float*)d_in[3];
    const float* b_gate = (const float*)d_in[4];
    const float* W_out  = (const float*)d_in[5];
    const float* b_out  = (const float*)d_in[6];
    const float* A_log  = (const float*)d_in[7];
    const float* B_mat  = (const float*)d_in[8];
    const float* C_mat  = (const float*)d_in[9];
    const float* D_vec  = (const float*)d_in[10];
    float* out = (float*)d_out;

    // workspace layout: f32 region first, bf16 after
    float* fws = (float*)d_ws;
    float* xproj = fws;                         //  4,194,304 f32
    float* delta = xproj + 4194304;             //  4,194,304 f32
    float* Q     = delta + 4194304;             //  2,097,152 f32
    float* hst   = Q + 2097152;                 //  2,097,152 f32
    float* sumdt = hst + 2097152;               //    131,072 f32
    unsigned short* us = (unsigned short*)(sumdt + 131072);
    unsigned short* gate  = us;                 //  4,194,304 bf16
    unsigned short* z     = gate  + 4194304;    //  4,194,304 bf16
    unsigned short* x_bf  = z     + 4194304;    //  2,097,152 bf16
    unsigned short* wg_bf = x_bf  + 2097152;    //  2,097,152 bf16
    unsigned short* wi_bf = wg_bf + 2097152;    //  4,194,304 bf16
    unsigned short* wo_bf = wi_bf + 4194304;    //  2,097,152 bf16

    dim3 blk(256);
    // cast (10240 blocks) + out=bias init (2048 blocks)
    cast_and_init<<<12288, blk, 0, stream>>>(x, W_gate, W_in, W_out,
                                             x_bf, wg_bf, wi_bf, wo_bf, b_out, out);
    // fused: gate = sigmoid(x@Wg^T+bg) -> bf16 ; proj -> xproj | relu delta (f32)
    gemm_mfma<3, 4><<<dim3(48, 16), blk, 0, stream>>>(
        x_bf, wg_bf, wi_bf, b_gate, b_in, gate, xproj, delta, nullptr, 1024, 1024);
    scan_phaseA<<<dim3(16, NC), blk, 0, stream>>>(xproj, delta, A_log, B_mat, Q, sumdt);
    scan_phaseB<<<256, blk, 0, stream>>>(A_log, Q, sumdt, hst);
    scan_phaseC<<<dim3(16, NC), blk, 0, stream>>>(xproj, delta, A_log, B_mat, C_mat, D_vec, gate, hst, z);
    // out += z @ W_out^T (K split in 4, atomic f32; out pre-initialized to bias)
    gemm_mfma<2, 2><<<dim3(8, 32, 4), blk, 0, stream>>>(
        z, wo_bf, nullptr, nullptr, nullptr, nullptr, nullptr, nullptr, out, 2048, 512);
}

// Round 7
// 208.462 us; speedup vs baseline: 1.1223x; 1.1223x over previous
//
#include <hip/hip_runtime.h>
#include <hip/hip_bf16.h>

// MambaStateSpaceLayer: B=2, S=1024, D_MODEL=1024, D_STATE=16, D_INNER=2048
// Round 7: r3 GEMM structure (single-buffer, 2-barrier, 32KB LDS, 768 blocks)
// + bf16 epilogue via LDS repack (full-line stores, no write amplification)
// + bf16 xproj/delta into scans (r4-validated numerics); gemm3 K-split x2.

#define LOG2E 1.4426950408889634f

typedef float floatx4 __attribute__((ext_vector_type(4)));
typedef short short8 __attribute__((ext_vector_type(8)));

__device__ __forceinline__ float fexp2(float x) { return __builtin_amdgcn_exp2f(x); }
__device__ __forceinline__ unsigned short f2bf(float f) {
    unsigned int u = __float_as_uint(f);
    u = (u + 0x7fffu + ((u >> 16) & 1u)) >> 16;   // round-to-nearest-even
    return (unsigned short)u;
}
__device__ __forceinline__ float bf2f(unsigned short h) {
    return __uint_as_float(((unsigned int)h) << 16);
}

// async 16B global -> LDS. lp MUST be wave-uniform (HW adds lane*16).
#define GLDS16(gp, lp) __builtin_amdgcn_global_load_lds(                      \
    (const __attribute__((address_space(1))) void*)(gp),                      \
    (__attribute__((address_space(3))) void*)(lp), 16, 0, 0)

// ------- cast x, W_gate, W_in, W_out to bf16 + init out=bias (one kernel) ----
__global__ __launch_bounds__(256) void cast_and_init(
    const float* __restrict__ x, const float* __restrict__ wg,
    const float* __restrict__ wi, const float* __restrict__ wo,
    unsigned short* __restrict__ ox, unsigned short* __restrict__ owg,
    unsigned short* __restrict__ owi, unsigned short* __restrict__ owo,
    const float* __restrict__ b_out, float* __restrict__ out)
{
    const int bid = blockIdx.x;
    if (bid < 10240) {
        const size_t e = ((size_t)bid * 256 + threadIdx.x) * 4;
        const float* src; unsigned short* dst; size_t off;
        if (e < 2097152)      { src = x;  dst = ox;  off = e; }
        else if (e < 4194304) { src = wg; dst = owg; off = e - 2097152; }
        else if (e < 8388608) { src = wi; dst = owi; off = e - 4194304; }
        else                  { src = wo; dst = owo; off = e - 8388608; }
        float4 v = *(const float4*)(src + off);
        *(ushort4*)(dst + off) = make_ushort4(f2bf(v.x), f2bf(v.y), f2bf(v.z), f2bf(v.w));
    } else {
        const size_t e = ((size_t)(bid - 10240) * 256 + threadIdx.x) * 4;
        const int col = (int)(e & 1023);
        *(float4*)(out + e) = *(const float4*)(b_out + col);
    }
}

// ---------------- MFMA GEMM (r3 structure) -----------------------------------
// C = A[M,ldk] @ W[N,ldk]^T (+ bias).  BK=64 bf16 (128B rows, 8x16B slots).
// Staging: global_load_lds dwordx4, linear LDS dest; source slot pre-swizzled
// (l&7)^(l>>3); ds_read uses slot ^ (row&7)  [both-sides-or-neither].
// Block = 4 waves (2x2). Wave tile = (MI*16) x 64. BM = MI*32, BN = 128.
// MODE 3 (MI=4): fused input GEMM. blockIdx.x<16 -> gate=sigmoid; else proj:
//   n<2048 -> xproj, n>=2048 -> relu -> delta.  ALL outputs bf16, written via
//   LDS repack (tile -> 32KB LDS as bf16 -> coalesced 16B/lane linear stores).
// MODE 2 (MI=2): K-split over blockIdx.z (Ksub each); atomicAdd f32 into outp.
template <int MODE, int MI>
__global__ __launch_bounds__(256, 3) void gemm_mfma(
    const unsigned short* __restrict__ A,
    const unsigned short* __restrict__ W0,
    const unsigned short* __restrict__ W1,
    const float* __restrict__ bias0, const float* __restrict__ bias1,
    unsigned short* __restrict__ gate,
    unsigned short* __restrict__ xproj, unsigned short* __restrict__ delta,
    float* __restrict__ outp, int ldk, int Ksub)
{
    constexpr int BM = MI * 32;
    constexpr int ROWA = BM / 32;          // A 1KB staging blocks per wave
    constexpr int NSH = (MODE == 3) ? 16384 : (BM * 64 + 8192);
    __shared__ short smem[NSH];            // staging; MODE 3 reuses as repack buf
    short* Asd = smem;                     // BM*64 shorts
    short* Bsd = smem + BM * 64;           // 128*64 shorts

    const int tid = threadIdx.x;
    const int l = tid & 63, w = tid >> 6;
    const int mbase = blockIdx.y * BM;
    const int kbeg = (MODE == 2) ? blockIdx.z * Ksub : 0;
    const int kend = kbeg + Ksub;

    const unsigned short* Wp; const float* bias = nullptr; int nbase; bool isGate = false;
    if (MODE == 3) {
        const int bx = blockIdx.x;
        if (bx < 16) { Wp = W0; bias = bias0; nbase = bx * 128; isGate = true; }
        else         { Wp = W1; bias = bias1; nbase = (bx - 16) * 128; }
    } else { Wp = W0; nbase = blockIdx.x * 128; }

    // per-lane staging source offsets (elements, k0 added per iter)
    const int rl = l >> 3;                 // row within 8-row block
    const int cs = (l & 7) ^ rl;           // inverse-swizzled source slot
    size_t aoff[ROWA], boff[4];
    #pragma unroll
    for (int j = 0; j < ROWA; ++j)
        aoff[j] = (size_t)(mbase + (w * ROWA + j) * 8 + rl) * ldk + cs * 8;
    #pragma unroll
    for (int j = 0; j < 4; ++j)
        boff[j] = (size_t)(nbase + (w * 4 + j) * 8 + rl) * ldk + cs * 8;

    const int wm = (w >> 1) * (MI * 16), wn = (w & 1) * 64;
    floatx4 acc[MI][4] = {};

    for (int k0 = kbeg; k0 < kend; k0 += 64) {
        __syncthreads();                   // prior tile's ds_reads complete
        #pragma unroll
        for (int j = 0; j < ROWA; ++j)
            GLDS16(A + aoff[j] + k0, &Asd[(w * ROWA + j) * 512]);
        #pragma unroll
        for (int j = 0; j < 4; ++j)
            GLDS16(Wp + boff[j] + k0, &Bsd[(w * 4 + j) * 512]);
        __syncthreads();                   // vmcnt(0) drained by compiler

        #pragma unroll
        for (int kk = 0; kk < 2; ++kk) {
            short8 af[MI], bfr[4];
            #pragma unroll
            for (int i = 0; i < MI; ++i) {
                const int row = wm + i * 16 + (l & 15);
                af[i] = *(const short8*)&Asd[row * 64 + (((kk * 4 + (l >> 4)) ^ (row & 7)) << 3)];
            }
            #pragma unroll
            for (int j = 0; j < 4; ++j) {
                const int row = wn + j * 16 + (l & 15);
                bfr[j] = *(const short8*)&Bsd[row * 64 + (((kk * 4 + (l >> 4)) ^ (row & 7)) << 3)];
            }
            #pragma unroll
            for (int i = 0; i < MI; ++i)
                #pragma unroll
                for (int j = 0; j < 4; ++j)
                    acc[i][j] = __builtin_amdgcn_mfma_f32_16x16x32_bf16(af[i], bfr[j], acc[i][j], 0, 0, 0);
        }
    }

    // epilogue: D col = lane&15, row = (lane>>4)*4 + reg  [m89-verified]
    const int mt = wm + (l >> 4) * 4;      // tile-local row base
    const int nt = wn + (l & 15);          // tile-local col base
    if (MODE == 3) {
        // 1) bf16 tile -> LDS [128][128]
        __syncthreads();                   // staging reads done; reuse smem
        unsigned short* lout = (unsigned short*)smem;
        #pragma unroll
        for (int j = 0; j < 4; ++j) {
            const float bb = bias[nbase + nt + j * 16];
            #pragma unroll
            for (int i = 0; i < MI; ++i) {
                #pragma unroll
                for (int r = 0; r < 4; ++r) {
                    float v = acc[i][j][r] + bb;
                    if (isGate) v = 1.0f / (1.0f + fexp2(-v * LOG2E));
                    else if (nbase >= 2048) v = fmaxf(v, 0.0f);
                    lout[(mt + i * 16 + r) * 128 + nt + j * 16] = f2bf(v);
                }
            }
        }
        __syncthreads();
        // 2) coalesced linear copy LDS -> global (full 64B+ lines)
        unsigned short* dst = isGate ? gate : (nbase < 2048 ? xproj : delta);
        const int ncb = nbase & 2047;      // col base within 2048-wide buffer
        #pragma unroll
        for (int it = 0; it < 8; ++it) {
            const int so = it * 2048 + tid * 8;       // short offset in tile
            const int mrow = so >> 7, ncol = so & 127;
            short8 v = *(const short8*)&lout[so];
            *(short8*)&dst[(size_t)(mbase + mrow) * 2048 + ncb + ncol] = v;
        }
    } else {
        #pragma unroll
        for (int j = 0; j < 4; ++j) {
            const int n = nbase + nt + j * 16;
            #pragma unroll
            for (int i = 0; i < MI; ++i) {
                #pragma unroll
                for (int r = 0; r < 4; ++r)
                    atomicAdd(&outp[(size_t)(mbase + mt + i * 16 + r) * 1024 + n],
                              acc[i][j][r]);
            }
        }
    }
}

// ---------------- chunked selective scan (bf16 xp/dl) ------------------------
constexpr int NC = 32, CL = 32;

__global__ __launch_bounds__(256) void scan_phaseA(
    const unsigned short* __restrict__ xp, const unsigned short* __restrict__ dl,
    const float* __restrict__ A_log, const float* __restrict__ B_mat,
    float* __restrict__ Q, float* __restrict__ sumdt)
{
    const int ch = blockIdx.x * 256 + threadIdx.x;
    const int c = blockIdx.y;
    const int d = ch & 2047, b = ch >> 11;
    float Ac[16], Bv[16], h[16];
    #pragma unroll
    for (int s = 0; s < 16; ++s) {
        Ac[s] = -fexp2(A_log[d * 16 + s] * LOG2E) * LOG2E;
        Bv[s] = B_mat[d * 16 + s];
        h[s] = 0.0f;
    }
    float sd = 0.0f;
    size_t idx = ((size_t)b * 1024 + (size_t)c * CL) * 2048 + d;
    for (int t = 0; t < CL; ++t, idx += 2048) {
        const float xt = bf2f(xp[idx]), dt = bf2f(dl[idx]);
        sd += dt;
        const float xdt = xt * dt;
        #pragma unroll
        for (int s = 0; s < 16; ++s)
            h[s] = fmaf(h[s], fexp2(Ac[s] * dt), xdt * Bv[s]);
    }
    float* q = Q + ((size_t)ch * NC + c) * 16;
    #pragma unroll
    for (int s = 0; s < 16; ++s) q[s] = h[s];
    sumdt[ch * NC + c] = sd;
}

__global__ __launch_bounds__(256) void scan_phaseB(
    const float* __restrict__ A_log, const float* __restrict__ Q,
    const float* __restrict__ sumdt, float* __restrict__ hst)
{
    const int s = threadIdx.x & 15;
    const int ch = blockIdx.x * 16 + (threadIdx.x >> 4);
    const int d = ch & 2047;
    const float Ac = -fexp2(A_log[d * 16 + s] * LOG2E) * LOG2E;
    float h = 0.0f;
    const float* q = Q + (size_t)ch * NC * 16 + s;
    const float* sd = sumdt + ch * NC;
    float* hs = hst + (size_t)ch * NC * 16 + s;
    for (int c = 0; c < NC; ++c) {
        hs[c * 16] = h;
        h = fmaf(h, fexp2(Ac * sd[c]), q[c * 16]);
    }
}

__global__ __launch_bounds__(256) void scan_phaseC(
    const unsigned short* __restrict__ xp, const unsigned short* __restrict__ dl,
    const float* __restrict__ A_log, const float* __restrict__ B_mat,
    const float* __restrict__ C_mat, const float* __restrict__ D_vec,
    const unsigned short* __restrict__ gate, const float* __restrict__ hst,
    unsigned short* __restrict__ z)
{
    const int ch = blockIdx.x * 256 + threadIdx.x;
    const int c = blockIdx.y;
    const int d = ch & 2047, b = ch >> 11;
    float Ac[16], Bv[16], Cv[16], h[16];
    #pragma unroll
    for (int s = 0; s < 16; ++s) {
        Ac[s] = -fexp2(A_log[d * 16 + s] * LOG2E) * LOG2E;
        Bv[s] = B_mat[d * 16 + s];
        Cv[s] = C_mat[s];
        h[s] = hst[((size_t)ch * NC + c) * 16 + s];
    }
    const float Dv = D_vec[d];
    size_t idx = ((size_t)b * 1024 + (size_t)c * CL) * 2048 + d;
    for (int t = 0; t < CL; ++t, idx += 2048) {
        const float xt = bf2f(xp[idx]), dt = bf2f(dl[idx]);
        const float xdt = xt * dt;
        float y = 0.0f;
        #pragma unroll
        for (int s = 0; s < 16; ++s) {
            h[s] = fmaf(h[s], fexp2(Ac[s] * dt), xdt * Bv[s]);
            y = fmaf(h[s], Cv[s], y);
        }
        const float g = bf2f(gate[idx]);
        z[idx] = f2bf(g * (y + xt * Dv));
    }
}

// ---------------------------------------------------------------------------
extern "C" void kernel_launch(void* const* d_in, const int* in_sizes, int n_in,
                              void* d_out, int out_size, void* d_ws, size_t ws_size,
                              hipStream_t stream) {
    const float* x      = (const float*)d_in[0];
    const float* W_in   = (const float*)d_in[1];
    const float* b_in   = (const float*)d_in[2];
    const float* W_gate = (const float*)d_in[3];
    const float* b_gate = (const float*)d_in[4];
    const float* W_out  = (const float*)d_in[5];
    const float* b_out  = (const float*)d_in[6];
    const float* A_log  = (const float*)d_in[7];
    const float* B_mat  = (const float*)d_in[8];
    const float* C_mat  = (const float*)d_in[9];
    const float* D_vec  = (const float*)d_in[10];
    float* out = (float*)d_out;

    // workspace: f32 region first, bf16 after
    float* fws = (float*)d_ws;
    float* Q     = fws;                         //  2,097,152 f32
    float* hst   = Q + 2097152;                 //  2,097,152 f32
    float* sumdt = hst + 2097152;               //    131,072 f32
    unsigned short* us = (unsigned short*)(sumdt + 131072);
    unsigned short* gate  = us;                 //  4,194,304 bf16
    unsigned short* z     = gate  + 4194304;    //  4,194,304 bf16
    unsigned short* xproj = z     + 4194304;    //  4,194,304 bf16
    unsigned short* delta = xproj + 4194304;    //  4,194,304 bf16
    unsigned short* x_bf  = delta + 4194304;    //  2,097,152 bf16
    unsigned short* wg_bf = x_bf  + 2097152;    //  2,097,152 bf16
    unsigned short* wi_bf = wg_bf + 2097152;    //  4,194,304 bf16
    unsigned short* wo_bf = wi_bf + 4194304;    //  2,097,152 bf16

    dim3 blk(256);
    // cast (10240 blocks) + out=bias init (2048 blocks)
    cast_and_init<<<12288, blk, 0, stream>>>(x, W_gate, W_in, W_out,
                                             x_bf, wg_bf, wi_bf, wo_bf, b_out, out);
    // fused: gate = sigmoid(x@Wg^T+bg) ; proj -> xproj | relu delta (all bf16)
    gemm_mfma<3, 4><<<dim3(48, 16), blk, 0, stream>>>(
        x_bf, wg_bf, wi_bf, b_gate, b_in, gate, xproj, delta, nullptr, 1024, 1024);
    scan_phaseA<<<dim3(16, NC), blk, 0, stream>>>(xproj, delta, A_log, B_mat, Q, sumdt);
    scan_phaseB<<<256, blk, 0, stream>>>(A_log, Q, sumdt, hst);
    scan_phaseC<<<dim3(16, NC), blk, 0, stream>>>(xproj, delta, A_log, B_mat, C_mat, D_vec, gate, hst, z);
    // out += z @ W_out^T (K split in 2, atomic f32; out pre-initialized to bias)
    gemm_mfma<2, 2><<<dim3(8, 32, 2), blk, 0, stream>>>(
        z, wo_bf, nullptr, nullptr, nullptr, nullptr, nullptr, nullptr, out, 2048, 1024);
}

// Round 8
// 205.402 us; speedup vs baseline: 1.1390x; 1.0149x over previous
//
#include <hip/hip_runtime.h>
#include <hip/hip_bf16.h>

// MambaStateSpaceLayer: B=2, S=1024, D_MODEL=1024, D_STATE=16, D_INNER=2048
// Round 8: r7 frozen except scan chunking NC 32->64 (CL=16): 1024-block scans
// (4/CU instead of 2/CU), half the serial chain per block.

#define LOG2E 1.4426950408889634f

typedef float floatx4 __attribute__((ext_vector_type(4)));
typedef short short8 __attribute__((ext_vector_type(8)));

__device__ __forceinline__ float fexp2(float x) { return __builtin_amdgcn_exp2f(x); }
__device__ __forceinline__ unsigned short f2bf(float f) {
    unsigned int u = __float_as_uint(f);
    u = (u + 0x7fffu + ((u >> 16) & 1u)) >> 16;   // round-to-nearest-even
    return (unsigned short)u;
}
__device__ __forceinline__ float bf2f(unsigned short h) {
    return __uint_as_float(((unsigned int)h) << 16);
}

// async 16B global -> LDS. lp MUST be wave-uniform (HW adds lane*16).
#define GLDS16(gp, lp) __builtin_amdgcn_global_load_lds(                      \
    (const __attribute__((address_space(1))) void*)(gp),                      \
    (__attribute__((address_space(3))) void*)(lp), 16, 0, 0)

// ------- cast x, W_gate, W_in, W_out to bf16 + init out=bias (one kernel) ----
__global__ __launch_bounds__(256) void cast_and_init(
    const float* __restrict__ x, const float* __restrict__ wg,
    const float* __restrict__ wi, const float* __restrict__ wo,
    unsigned short* __restrict__ ox, unsigned short* __restrict__ owg,
    unsigned short* __restrict__ owi, unsigned short* __restrict__ owo,
    const float* __restrict__ b_out, float* __restrict__ out)
{
    const int bid = blockIdx.x;
    if (bid < 10240) {
        const size_t e = ((size_t)bid * 256 + threadIdx.x) * 4;
        const float* src; unsigned short* dst; size_t off;
        if (e < 2097152)      { src = x;  dst = ox;  off = e; }
        else if (e < 4194304) { src = wg; dst = owg; off = e - 2097152; }
        else if (e < 8388608) { src = wi; dst = owi; off = e - 4194304; }
        else                  { src = wo; dst = owo; off = e - 8388608; }
        float4 v = *(const float4*)(src + off);
        *(ushort4*)(dst + off) = make_ushort4(f2bf(v.x), f2bf(v.y), f2bf(v.z), f2bf(v.w));
    } else {
        const size_t e = ((size_t)(bid - 10240) * 256 + threadIdx.x) * 4;
        const int col = (int)(e & 1023);
        *(float4*)(out + e) = *(const float4*)(b_out + col);
    }
}

// ---------------- MFMA GEMM (r3 structure, r7 epilogue) ----------------------
// C = A[M,ldk] @ W[N,ldk]^T (+ bias).  BK=64 bf16 (128B rows, 8x16B slots).
// Staging: global_load_lds dwordx4, linear LDS dest; source slot pre-swizzled
// (l&7)^(l>>3); ds_read uses slot ^ (row&7)  [both-sides-or-neither].
// Block = 4 waves (2x2). Wave tile = (MI*16) x 64. BM = MI*32, BN = 128.
// MODE 3 (MI=4): fused input GEMM. blockIdx.x<16 -> gate=sigmoid; else proj:
//   n<2048 -> xproj, n>=2048 -> relu -> delta.  ALL outputs bf16, written via
//   LDS repack (tile -> 32KB LDS as bf16 -> coalesced 16B/lane linear stores).
// MODE 2 (MI=2): K-split over blockIdx.z (Ksub each); atomicAdd f32 into outp.
template <int MODE, int MI>
__global__ __launch_bounds__(256, 3) void gemm_mfma(
    const unsigned short* __restrict__ A,
    const unsigned short* __restrict__ W0,
    const unsigned short* __restrict__ W1,
    const float* __restrict__ bias0, const float* __restrict__ bias1,
    unsigned short* __restrict__ gate,
    unsigned short* __restrict__ xproj, unsigned short* __restrict__ delta,
    float* __restrict__ outp, int ldk, int Ksub)
{
    constexpr int BM = MI * 32;
    constexpr int ROWA = BM / 32;          // A 1KB staging blocks per wave
    constexpr int NSH = (MODE == 3) ? 16384 : (BM * 64 + 8192);
    __shared__ short smem[NSH];            // staging; MODE 3 reuses as repack buf
    short* Asd = smem;                     // BM*64 shorts
    short* Bsd = smem + BM * 64;           // 128*64 shorts

    const int tid = threadIdx.x;
    const int l = tid & 63, w = tid >> 6;
    const int mbase = blockIdx.y * BM;
    const int kbeg = (MODE == 2) ? blockIdx.z * Ksub : 0;
    const int kend = kbeg + Ksub;

    const unsigned short* Wp; const float* bias = nullptr; int nbase; bool isGate = false;
    if (MODE == 3) {
        const int bx = blockIdx.x;
        if (bx < 16) { Wp = W0; bias = bias0; nbase = bx * 128; isGate = true; }
        else         { Wp = W1; bias = bias1; nbase = (bx - 16) * 128; }
    } else { Wp = W0; nbase = blockIdx.x * 128; }

    // per-lane staging source offsets (elements, k0 added per iter)
    const int rl = l >> 3;                 // row within 8-row block
    const int cs = (l & 7) ^ rl;           // inverse-swizzled source slot
    size_t aoff[ROWA], boff[4];
    #pragma unroll
    for (int j = 0; j < ROWA; ++j)
        aoff[j] = (size_t)(mbase + (w * ROWA + j) * 8 + rl) * ldk + cs * 8;
    #pragma unroll
    for (int j = 0; j < 4; ++j)
        boff[j] = (size_t)(nbase + (w * 4 + j) * 8 + rl) * ldk + cs * 8;

    const int wm = (w >> 1) * (MI * 16), wn = (w & 1) * 64;
    floatx4 acc[MI][4] = {};

    for (int k0 = kbeg; k0 < kend; k0 += 64) {
        __syncthreads();                   // prior tile's ds_reads complete
        #pragma unroll
        for (int j = 0; j < ROWA; ++j)
            GLDS16(A + aoff[j] + k0, &Asd[(w * ROWA + j) * 512]);
        #pragma unroll
        for (int j = 0; j < 4; ++j)
            GLDS16(Wp + boff[j] + k0, &Bsd[(w * 4 + j) * 512]);
        __syncthreads();                   // vmcnt(0) drained by compiler

        #pragma unroll
        for (int kk = 0; kk < 2; ++kk) {
            short8 af[MI], bfr[4];
            #pragma unroll
            for (int i = 0; i < MI; ++i) {
                const int row = wm + i * 16 + (l & 15);
                af[i] = *(const short8*)&Asd[row * 64 + (((kk * 4 + (l >> 4)) ^ (row & 7)) << 3)];
            }
            #pragma unroll
            for (int j = 0; j < 4; ++j) {
                const int row = wn + j * 16 + (l & 15);
                bfr[j] = *(const short8*)&Bsd[row * 64 + (((kk * 4 + (l >> 4)) ^ (row & 7)) << 3)];
            }
            #pragma unroll
            for (int i = 0; i < MI; ++i)
                #pragma unroll
                for (int j = 0; j < 4; ++j)
                    acc[i][j] = __builtin_amdgcn_mfma_f32_16x16x32_bf16(af[i], bfr[j], acc[i][j], 0, 0, 0);
        }
    }

    // epilogue: D col = lane&15, row = (lane>>4)*4 + reg  [m89-verified]
    const int mt = wm + (l >> 4) * 4;      // tile-local row base
    const int nt = wn + (l & 15);          // tile-local col base
    if (MODE == 3) {
        // 1) bf16 tile -> LDS [128][128]
        __syncthreads();                   // staging reads done; reuse smem
        unsigned short* lout = (unsigned short*)smem;
        #pragma unroll
        for (int j = 0; j < 4; ++j) {
            const float bb = bias[nbase + nt + j * 16];
            #pragma unroll
            for (int i = 0; i < MI; ++i) {
                #pragma unroll
                for (int r = 0; r < 4; ++r) {
                    float v = acc[i][j][r] + bb;
                    if (isGate) v = 1.0f / (1.0f + fexp2(-v * LOG2E));
                    else if (nbase >= 2048) v = fmaxf(v, 0.0f);
                    lout[(mt + i * 16 + r) * 128 + nt + j * 16] = f2bf(v);
                }
            }
        }
        __syncthreads();
        // 2) coalesced linear copy LDS -> global (full 64B+ lines)
        unsigned short* dst = isGate ? gate : (nbase < 2048 ? xproj : delta);
        const int ncb = nbase & 2047;      // col base within 2048-wide buffer
        #pragma unroll
        for (int it = 0; it < 8; ++it) {
            const int so = it * 2048 + tid * 8;       // short offset in tile
            const int mrow = so >> 7, ncol = so & 127;
            short8 v = *(const short8*)&lout[so];
            *(short8*)&dst[(size_t)(mbase + mrow) * 2048 + ncb + ncol] = v;
        }
    } else {
        #pragma unroll
        for (int j = 0; j < 4; ++j) {
            const int n = nbase + nt + j * 16;
            #pragma unroll
            for (int i = 0; i < MI; ++i) {
                #pragma unroll
                for (int r = 0; r < 4; ++r)
                    atomicAdd(&outp[(size_t)(mbase + mt + i * 16 + r) * 1024 + n],
                              acc[i][j][r]);
            }
        }
    }
}

// ---------------- chunked selective scan (bf16 xp/dl), NC=64 -----------------
constexpr int NC = 64, CL = 16;

__global__ __launch_bounds__(256) void scan_phaseA(
    const unsigned short* __restrict__ xp, const unsigned short* __restrict__ dl,
    const float* __restrict__ A_log, const float* __restrict__ B_mat,
    float* __restrict__ Q, float* __restrict__ sumdt)
{
    const int ch = blockIdx.x * 256 + threadIdx.x;
    const int c = blockIdx.y;
    const int d = ch & 2047, b = ch >> 11;
    float Ac[16], Bv[16], h[16];
    #pragma unroll
    for (int s = 0; s < 16; ++s) {
        Ac[s] = -fexp2(A_log[d * 16 + s] * LOG2E) * LOG2E;
        Bv[s] = B_mat[d * 16 + s];
        h[s] = 0.0f;
    }
    float sd = 0.0f;
    size_t idx = ((size_t)b * 1024 + (size_t)c * CL) * 2048 + d;
    for (int t = 0; t < CL; ++t, idx += 2048) {
        const float xt = bf2f(xp[idx]), dt = bf2f(dl[idx]);
        sd += dt;
        const float xdt = xt * dt;
        #pragma unroll
        for (int s = 0; s < 16; ++s)
            h[s] = fmaf(h[s], fexp2(Ac[s] * dt), xdt * Bv[s]);
    }
    float* q = Q + ((size_t)ch * NC + c) * 16;
    #pragma unroll
    for (int s = 0; s < 16; ++s) q[s] = h[s];
    sumdt[ch * NC + c] = sd;
}

__global__ __launch_bounds__(256) void scan_phaseB(
    const float* __restrict__ A_log, const float* __restrict__ Q,
    const float* __restrict__ sumdt, float* __restrict__ hst)
{
    const int s = threadIdx.x & 15;
    const int ch = blockIdx.x * 16 + (threadIdx.x >> 4);
    const int d = ch & 2047;
    const float Ac = -fexp2(A_log[d * 16 + s] * LOG2E) * LOG2E;
    float h = 0.0f;
    const float* q = Q + (size_t)ch * NC * 16 + s;
    const float* sd = sumdt + ch * NC;
    float* hs = hst + (size_t)ch * NC * 16 + s;
    for (int c = 0; c < NC; ++c) {
        hs[c * 16] = h;
        h = fmaf(h, fexp2(Ac * sd[c]), q[c * 16]);
    }
}

__global__ __launch_bounds__(256) void scan_phaseC(
    const unsigned short* __restrict__ xp, const unsigned short* __restrict__ dl,
    const float* __restrict__ A_log, const float* __restrict__ B_mat,
    const float* __restrict__ C_mat, const float* __restrict__ D_vec,
    const unsigned short* __restrict__ gate, const float* __restrict__ hst,
    unsigned short* __restrict__ z)
{
    const int ch = blockIdx.x * 256 + threadIdx.x;
    const int c = blockIdx.y;
    const int d = ch & 2047, b = ch >> 11;
    float Ac[16], Bv[16], Cv[16], h[16];
    #pragma unroll
    for (int s = 0; s < 16; ++s) {
        Ac[s] = -fexp2(A_log[d * 16 + s] * LOG2E) * LOG2E;
        Bv[s] = B_mat[d * 16 + s];
        Cv[s] = C_mat[s];
        h[s] = hst[((size_t)ch * NC + c) * 16 + s];
    }
    const float Dv = D_vec[d];
    size_t idx = ((size_t)b * 1024 + (size_t)c * CL) * 2048 + d;
    for (int t = 0; t < CL; ++t, idx += 2048) {
        const float xt = bf2f(xp[idx]), dt = bf2f(dl[idx]);
        const float xdt = xt * dt;
        float y = 0.0f;
        #pragma unroll
        for (int s = 0; s < 16; ++s) {
            h[s] = fmaf(h[s], fexp2(Ac[s] * dt), xdt * Bv[s]);
            y = fmaf(h[s], Cv[s], y);
        }
        const float g = bf2f(gate[idx]);
        z[idx] = f2bf(g * (y + xt * Dv));
    }
}

// ---------------------------------------------------------------------------
extern "C" void kernel_launch(void* const* d_in, const int* in_sizes, int n_in,
                              void* d_out, int out_size, void* d_ws, size_t ws_size,
                              hipStream_t stream) {
    const float* x      = (const float*)d_in[0];
    const float* W_in   = (const float*)d_in[1];
    const float* b_in   = (const float*)d_in[2];
    const float* W_gate = (const float*)d_in[3];
    const float* b_gate = (const float*)d_in[4];
    const float* W_out  = (const float*)d_in[5];
    const float* b_out  = (const float*)d_in[6];
    const float* A_log  = (const float*)d_in[7];
    const float* B_mat  = (const float*)d_in[8];
    const float* C_mat  = (const float*)d_in[9];
    const float* D_vec  = (const float*)d_in[10];
    float* out = (float*)d_out;

    // workspace: f32 region first, bf16 after
    float* fws = (float*)d_ws;
    float* Q     = fws;                         //  4,194,304 f32 (4096*64*16)
    float* hst   = Q + 4194304;                 //  4,194,304 f32
    float* sumdt = hst + 4194304;               //    262,144 f32
    unsigned short* us = (unsigned short*)(sumdt + 262144);
    unsigned short* gate  = us;                 //  4,194,304 bf16
    unsigned short* z     = gate  + 4194304;    //  4,194,304 bf16
    unsigned short* xproj = z     + 4194304;    //  4,194,304 bf16
    unsigned short* delta = xproj + 4194304;    //  4,194,304 bf16
    unsigned short* x_bf  = delta + 4194304;    //  2,097,152 bf16
    unsigned short* wg_bf = x_bf  + 2097152;    //  2,097,152 bf16
    unsigned short* wi_bf = wg_bf + 2097152;    //  4,194,304 bf16
    unsigned short* wo_bf = wi_bf + 4194304;    //  2,097,152 bf16

    dim3 blk(256);
    // cast (10240 blocks) + out=bias init (2048 blocks)
    cast_and_init<<<12288, blk, 0, stream>>>(x, W_gate, W_in, W_out,
                                             x_bf, wg_bf, wi_bf, wo_bf, b_out, out);
    // fused: gate = sigmoid(x@Wg^T+bg) ; proj -> xproj | relu delta (all bf16)
    gemm_mfma<3, 4><<<dim3(48, 16), blk, 0, stream>>>(
        x_bf, wg_bf, wi_bf, b_gate, b_in, gate, xproj, delta, nullptr, 1024, 1024);
    scan_phaseA<<<dim3(16, NC), blk, 0, stream>>>(xproj, delta, A_log, B_mat, Q, sumdt);
    scan_phaseB<<<256, blk, 0, stream>>>(A_log, Q, sumdt, hst);
    scan_phaseC<<<dim3(16, NC), blk, 0, stream>>>(xproj, delta, A_log, B_mat, C_mat, D_vec, gate, hst, z);
    // out += z @ W_out^T (K split in 2, atomic f32; out pre-initialized to bias)
    gemm_mfma<2, 2><<<dim3(8, 32, 2), blk, 0, stream>>>(
        z, wo_bf, nullptr, nullptr, nullptr, nullptr, nullptr, nullptr, out, 2048, 1024);
}